// Round 1
// 131.832 us; speedup vs baseline: 1.0110x; 1.0110x over previous
//
#include <hip/hip_runtime.h>
#include <cstdint>
#include <cstddef>

// Problem constants
#define BB 4
#define NN 20000
#define KK 16
#define MM 9
#define CC 64
#define OO 64
#define BN (BB*NN)       // 80000 nodes
#define MC (MM*CC)       // 576 flattened reduction dim
#define UVP 12           // padded ux/vx row (9 used + 3 pad) fp32
#define QNP 160          // qlds node pitch (u16): 9*16=144 used, rest pad
#define QTAIL 128        // tail pad for benign lr>=9 over-read
#define NKS (MC/32)      // 18 K-steps in Phase C
#define NCHUNK16 1250    // 16-node chunks per batch

typedef _Float16 f16x8 __attribute__((ext_vector_type(8)));
typedef _Float16 f16x4 __attribute__((ext_vector_type(4)));
typedef __fp16   fp16v2 __attribute__((ext_vector_type(2)));   // pkrtz return type
typedef float    f32x4 __attribute__((ext_vector_type(4)));
typedef unsigned short u16;
typedef unsigned int   u32;

union Hcv { _Float16 h; u16 u; };
__device__ __forceinline__ u16 f2h(float f) { Hcv t; t.h = (_Float16)f; return t.u; }
__device__ __forceinline__ float h2f(u16 h) { Hcv t; t.u = h; return (float)t.h; }

// ---------------------------------------------------------------------------
// Pre-pass (unchanged): blocks < 1250: uxvx GEMM for 64 nodes AND xh side-write.
// Blocks 1250..1285: W -> wfb2 fragment-order swizzle.
// ---------------------------------------------------------------------------
__global__ __launch_bounds__(256) void pre_kernel(
    const float* __restrict__ x, const float* __restrict__ W,
    const float* __restrict__ u, const float* __restrict__ v,
    const float* __restrict__ c,
    float* __restrict__ uxc, float* __restrict__ vxp,
    u16* __restrict__ xh, u16* __restrict__ wfb2)
{
    const int bid = blockIdx.x;
    if (bid >= 1250) {                        // W swizzle: 36*1024 = 36864 elems
        int base = (bid - 1250) * 1024 + threadIdx.x * 4;
        ushort4 wv;
        u16* wp = (u16*)&wv;
        #pragma unroll
        for (int t = 0; t < 4; ++t) {
            int i = base + t;
            int j = i & 7, o = (i >> 3) & 63, l2 = (i >> 9) & 3, ks = i >> 11;
            int kf = ks * 32 + l2 * 8 + j;
            int m = kf >> 6, cc2 = kf & 63;
            wp[t] = f2h(W[m * 4096 + o * 64 + cc2]);
        }
        *(ushort4*)(wfb2 + base) = wv;
        return;
    }
    const int wave = threadIdx.x >> 6, lane = threadIdx.x & 63;
    const int lr = lane & 15, lhi = lane >> 4;
    const int t0n = bid * 64 + wave * 16;

    const float* xr = x + (size_t)(t0n + lr) * 64 + lhi * 8;
    float xf[16];
    *(float4*)(xf + 0)  = *(const float4*)(xr + 0);
    *(float4*)(xf + 4)  = *(const float4*)(xr + 4);
    *(float4*)(xf + 8)  = *(const float4*)(xr + 32);
    *(float4*)(xf + 12) = *(const float4*)(xr + 36);
    union { u16 us[8]; f16x8 v; ushort4 s4[2]; } H0, L0, H1, L1;
    #pragma unroll
    for (int i = 0; i < 8; ++i) {
        u16 h = f2h(xf[i]);      H0.us[i] = h;  L0.us[i] = f2h(xf[i] - h2f(h));
        u16 h2 = f2h(xf[8 + i]); H1.us[i] = h2; L1.us[i] = f2h(xf[8 + i] - h2f(h2));
    }
    *(ushort4*)(xh + (size_t)(t0n + lr) * 64 + lhi * 8)      = H0.s4[0];
    *(ushort4*)(xh + (size_t)(t0n + lr) * 64 + lhi * 8 + 4)  = H0.s4[1];
    *(ushort4*)(xh + (size_t)(t0n + lr) * 64 + 32 + lhi * 8)     = H1.s4[0];
    *(ushort4*)(xh + (size_t)(t0n + lr) * 64 + 32 + lhi * 8 + 4) = H1.s4[1];

    f32x4 acc0 = {0.f,0.f,0.f,0.f}, acc1 = {0.f,0.f,0.f,0.f};
    #pragma unroll
    for (int t = 0; t < 2; ++t) {
        int r = t * 16 + lr;
        const float* gp = (r < 9) ? (u + r * 64) : (v + (r - 9) * 64);
        bool nz = r < 18;
        f32x4 acc = {0.f,0.f,0.f,0.f};
        #pragma unroll
        for (int s = 0; s < 2; ++s) {
            float gf[8];
            *(float4*)(gf + 0) = nz ? *(const float4*)(gp + s * 32 + lhi * 8)
                                    : make_float4(0.f,0.f,0.f,0.f);
            *(float4*)(gf + 4) = nz ? *(const float4*)(gp + s * 32 + lhi * 8 + 4)
                                    : make_float4(0.f,0.f,0.f,0.f);
            union { u16 us[8]; f16x8 v; } GH, GL;
            #pragma unroll
            for (int i = 0; i < 8; ++i) {
                u16 h = f2h(gf[i]); GH.us[i] = h; GL.us[i] = f2h(gf[i] - h2f(h));
            }
            f16x8 as  = s ? H1.v : H0.v;
            f16x8 asl = s ? L1.v : L0.v;
            acc = __builtin_amdgcn_mfma_f32_16x16x32_f16(as,  GH.v, acc, 0, 0, 0);
            acc = __builtin_amdgcn_mfma_f32_16x16x32_f16(as,  GL.v, acc, 0, 0, 0);
            acc = __builtin_amdgcn_mfma_f32_16x16x32_f16(asl, GH.v, acc, 0, 0, 0);
        }
        if (t == 0) acc0 = acc; else acc1 = acc;
    }
    float cv = (lr < 9) ? c[lr] : 0.f;
    #pragma unroll
    for (int reg = 0; reg < 4; ++reg) {
        int node = t0n + lhi * 4 + reg;
        if (lr < 9) uxc[(size_t)node * UVP + lr] = acc0[reg] + cv;
        else        vxp[(size_t)node * UVP + (lr - 9)] = acc0[reg];
        if (lr < 2) vxp[(size_t)node * UVP + 7 + lr] = acc1[reg];
    }
}

// ---------------------------------------------------------------------------
// Fused, restructured to 16-node blocks (one tile, ONE barrier):
//   gathers issued early -> Phase A softmax -> Bcomp -> bar -> C.
// LDS 23808 B -> 6 blocks/CU co-resident (was 38400 B -> 4); hardware TLP
// replaces the old 2-tile software pipeline.
// slds layout: chunked [q=kf>>3][node][16B], XOR-swizzled by m into the node
// bits (idx16 ^= (m&7)<<3). C-phase ds_read_b128 is lane-linear 16B chunks
// (conflict-free); Bcomp 8B writes land ~2-way (free per m136).
// XCD swizzle: XCD pair {2b,2b+1} owns batch b; grid exactly 5000, no waste.
// Layouts (m89/m101/m121-128 verified): 16x16x32: A row=lane&15,
// k=(lane>>4)*8+j; 16x16x16: A row=lane&15, k=(lane>>4)*4+j; B mirrors A
// with col=lane&15; D col=lane&15, row=(lane>>4)*4+reg.
// ---------------------------------------------------------------------------
__global__ __launch_bounds__(256, 6) void fused_kernel(
    const u16* __restrict__ xh, const int* __restrict__ adj,
    const float* __restrict__ uxc, const float* __restrict__ vxp,
    const u16* __restrict__ wfb2, const float* __restrict__ bias,
    float* __restrict__ out)
{
    __shared__ __align__(16) u16 qlds[16 * QNP + QTAIL];   // 5376 B
    __shared__ __align__(16) u16 slds[72 * 16 * 8];        // 18432 B
    const int bid = blockIdx.x;
    const int grp = bid & 7;                       // XCD id (round-robin)
    const int b = grp >> 1;                        // batch owned by XCD pair
    const int chunk = (bid >> 3) * 2 + (grp & 1);  // 0..1249
    const int tid = threadIdx.x, wave = tid >> 6, lane = tid & 63;
    const int lr = lane & 15, lhi = lane >> 4;
    const int node0 = b * NN + chunk * 16;
    const int rowbase = b * NN;
    const u16* xhb = xh + ((size_t)rowbase << 6);

    // adj for this tile: thread tid <-> (node tid>>4 = wave*4+lhi, k = lr)
    int jj = adj[(size_t)node0 * KK + tid];

    // ---- xh gathers issued EARLY: L2 latency hides under Phase A ----
    f16x8 aLo[4], aHi[4];
    #pragma unroll
    for (int g2 = 0; g2 < 4; ++g2) {
        int e = __builtin_amdgcn_ds_bpermute((g2 * 16 + lr) * 4, jj);
        int erow = ((e > 0) ? e : 1) - 1;          // pad -> row 0 (q=0 kills)
        const u16* rp = xhb + ((size_t)erow << 6) + lhi * 8;
        aLo[g2] = *(const f16x8*)(rp);
        aHi[g2] = *(const f16x8*)(rp + 32);
    }

    // ---- Phase A: logits + softmax over M, q -> qlds ----
    {
        unsigned long long bal = __ballot(jj != 0);
        int deg = __popcll((bal >> (lhi * 16)) & 0xffffull);
        float inv = (deg > 0) ? (1.0f / (float)deg) : 0.0f;
        const int node = node0 + wave * 4 + lhi;
        float q[MM];
        #pragma unroll
        for (int m = 0; m < MM; ++m) q[m] = 0.f;
        if (jj != 0) {
            const float4* ur = (const float4*)(uxc + (size_t)node * UVP);
            const float4* vr = (const float4*)(vxp + ((size_t)rowbase + (jj - 1)) * UVP);
            float4 u0 = ur[0], u1 = ur[1], u2 = ur[2];
            float4 v0 = vr[0], v1 = vr[1], v2 = vr[2];
            float l[MM] = { u0.x+v0.x, u0.y+v0.y, u0.z+v0.z, u0.w+v0.w,
                            u1.x+v1.x, u1.y+v1.y, u1.z+v1.z, u1.w+v1.w,
                            u2.x+v2.x };
            float mx = l[0];
            #pragma unroll
            for (int m = 1; m < MM; ++m) mx = fmaxf(mx, l[m]);
            float sum = 0.f;
            #pragma unroll
            for (int m = 0; m < MM; ++m) { l[m] = __expf(l[m] - mx); sum += l[m]; }
            float sc = inv / sum;
            #pragma unroll
            for (int m = 0; m < MM; ++m) q[m] = l[m] * sc;
        }
        u16* qw = qlds + (wave * 4 + lhi) * QNP + lr;
        #pragma unroll
        for (int m = 0; m < MM; ++m) qw[m * 16] = f2h(q[m]);
    }

    // qf read: same wave wrote it -> no barrier needed (in-wave lgkmcnt order)
    f16x4 qf[4];
    #pragma unroll
    for (int g2 = 0; g2 < 4; ++g2)
        qf[g2] = *(const f16x4*)(qlds + (wave * 4 + g2) * QNP + lr * 16 + lhi * 4);

    // identity-selector B-frags for the transpose-MFMA
    f16x8 idf[2];
    #pragma unroll
    for (int s = 0; s < 2; ++s) {
        union { u16 us[8]; f16x8 v; } t;
        #pragma unroll
        for (int j = 0; j < 8; ++j)
            t.us[j] = (lhi * 8 + j == s * 16 + lr) ? (u16)0x3C00 : (u16)0;
        idf[s] = t.v;
    }

    // ---- Bcomp -> slds (chunked + XOR-swizzled) ----
    #pragma unroll
    for (int g2 = 0; g2 < 4; ++g2) {
        const int rnode = wave * 4 + g2;
        #pragma unroll
        for (int cc = 0; cc < 4; ++cc) {
            f32x4 xt = {0.f,0.f,0.f,0.f};
            xt = __builtin_amdgcn_mfma_f32_16x16x32_f16(
                     (cc < 2) ? aLo[g2] : aHi[g2], idf[cc & 1], xt, 0, 0, 0);
            union { fp16v2 h2[2]; f16x4 h4; } at;
            at.h2[0] = __builtin_amdgcn_cvt_pkrtz(xt[0], xt[1]);
            at.h2[1] = __builtin_amdgcn_cvt_pkrtz(xt[2], xt[3]);
            f32x4 d2 = {0.f,0.f,0.f,0.f};
            d2 = __builtin_amdgcn_mfma_f32_16x16x16f16(at.h4, qf[g2], d2, 0, 0, 0);
            if (lr < 9) {
                u32 lo = __builtin_amdgcn_perm((u32)f2h(d2[1]), (u32)f2h(d2[0]), 0x05040100u);
                u32 hi = __builtin_amdgcn_perm((u32)f2h(d2[3]), (u32)f2h(d2[2]), 0x05040100u);
                // kf = lr*64 + cc*16 + lhi*4 ; q = kf>>3 = lr*8 + cc*2 + (lhi>>1)
                // m = kf>>6 = lr ; in-chunk byte = (kf&7)*2 = (lhi&1)*8
                int q_ = lr * 8 + cc * 2 + (lhi >> 1);
                int idx16 = (((q_ * 16 + rnode) << 3) ^ ((lr & 7) << 3)) + (lhi & 1) * 4;
                *(uint2*)(slds + idx16) = make_uint2(lo, hi);
            }
        }
    }
    __syncthreads();

    // ---- Phase C: out = s . W ----
    const int o0 = wave * 16;
    float bv = bias[o0 + lr];
    f32x4 acc = {0.f,0.f,0.f,0.f};
    #pragma unroll
    for (int ks = 0; ks < NKS; ++ks) {
        // kf = ks*32 + lhi*8 ; q = ks*4 + lhi ; m = q>>3 (wave-uniform per ks)
        int q_ = ks * 4 + lhi;
        int idx16 = ((q_ * 16 + lr) << 3) ^ (((q_ >> 3) & 7) << 3);
        f16x8 afrag = *(const f16x8*)(slds + idx16);
        f16x8 bfrag = *(const f16x8*)(wfb2 + (size_t)(((ks * 4 + lhi) * 64) + o0 + lr) * 8);
        acc = __builtin_amdgcn_mfma_f32_16x16x32_f16(afrag, bfrag, acc, 0, 0, 0);
    }
    #pragma unroll
    for (int reg = 0; reg < 4; ++reg) {
        int rr = node0 + lhi * 4 + reg;
        out[(size_t)rr * OO + o0 + lr] = acc[reg] + bv;
    }
}

// ---------------------------------------------------------------------------
extern "C" void kernel_launch(void* const* d_in, const int* in_sizes, int n_in,
                              void* d_out, int out_size, void* d_ws, size_t ws_size,
                              hipStream_t stream)
{
    const float* x   = (const float*)d_in[0];
    const int*   adj = (const int*)  d_in[1];
    const float* W   = (const float*)d_in[2];
    const float* b   = (const float*)d_in[3];
    const float* u   = (const float*)d_in[4];
    const float* v   = (const float*)d_in[5];
    const float* c   = (const float*)d_in[6];
    float* out = (float*)d_out;

    // workspace layout (16B-aligned sections):
    //   uxc f32 [BN*12] | vxp f32 [BN*12] | xh f16 [BN*64] | wfb2 f16 [36864]
    float* uxc = (float*)d_ws;
    float* vxp = uxc + (size_t)BN * UVP;
    u16*   xh  = (u16*)(vxp + (size_t)BN * UVP);
    u16*   wfb2= xh + (size_t)BN * CC;

    pre_kernel<<<1286, 256, 0, stream>>>(x, W, u, v, c, uxc, vxp, xh, wfb2);
    fused_kernel<<<5000, 256, 0, stream>>>(xh, adj, uxc, vxp, wfb2, b, out);
}